// Round 12
// baseline (372.121 us; speedup 1.0000x reference)
//
#include <hip/hip_runtime.h>
#include <hip/hip_cooperative_groups.h>
#include <hip/hip_bf16.h>
#include <math.h>

namespace cg = cooperative_groups;

typedef __attribute__((ext_vector_type(4))) float f32x4;
typedef __attribute__((ext_vector_type(16))) float f32x16;
typedef __attribute__((ext_vector_type(8))) int i32x8;
typedef __attribute__((ext_vector_type(4))) int i32x4;

#define TEMP_INV 14.2857142857142857f     // 1/0.07
#define SCALE_EPI 0.013950892857142857f   // TEMP_INV / 1024 (32*32 prescale)
#define UNIT_SCALE 0x7f7f7f7f             // E8M0 127 -> x1.0 exact (verified)

union frag32 {
  i32x8 v8;
  struct { i32x4 lo; i32x4 hi; } s;
};

// ---- async global->LDS, 16B per lane
static __device__ inline void async16(const void* g, void* l) {
  __builtin_amdgcn_global_load_lds(
      (const __attribute__((address_space(1))) unsigned int*)g,
      (__attribute__((address_space(3))) unsigned int*)l,
      16, 0, 0);
}

// ---- OCP fp4 e2m1 encode (verified R8-R11, absmax 0.031)
static __device__ inline int fp4e(float y) {
  const float af = fabsf(y);
  int code = (af > 0.25f) + (af > 0.75f) + (af > 1.25f) + (af > 1.75f) +
             (af > 2.5f) + (af > 3.5f) + (af > 5.0f);
  return code | (y < 0.f ? 8 : 0);
}

// ============================================================
// Fragment-major MX-fp4 format (verified R8-R11):
//   panel p = 32 rows, k-step s = 64 K-elems. record(p,s) = 1 KB at
//   (p*16+s)*1024. Lane l: row p*32+(l&31), k-elems s*64+(l>>5)*32..
//   16 B at rec + l*16. Values are 32*x (exact pow-2 prescale).
// ============================================================

// ============================================================
// FUSED cooperative kernel: 1024 blocks x 256 thr, 32 KB LDS,
// launch_bounds(256,4) -> exactly 4 blocks/CU co-resident.
// Phase 1: 2 blocks/panel normalize->fp4 (verified algebra).
// grid.sync (device-scope fence: fp4 + pos/neg visible)
// Phase 2: 4 GEMM tiles/block (R11 K-loop + swapped-operand epilogue).
// grid.sync
// Phase 3: blocks 0..7 final reduce -> atomic mean.
// ============================================================
__global__ __launch_bounds__(256, 4) void fused_all(
    const float* __restrict__ a, const float* __restrict__ b,
    unsigned char* __restrict__ oa, unsigned char* __restrict__ ob,
    const int* __restrict__ la, const int* __restrict__ lb,
    float* __restrict__ pos_acc, float* __restrict__ neg_acc,
    float* __restrict__ dout) {
  __shared__ __align__(16) unsigned char sA[16384];
  __shared__ __align__(16) unsigned char sB[16384];

  const int tid = threadIdx.x;
  const int bid = blockIdx.x;

  // ---------------- Phase 1: normalize 16 rows -> fp4 ----------------
  {
    const int pg = bid >> 1;   // panel 0..511
    const int sub = bid & 1;   // 16-row half
    const bool isA = pg < 256;
    const int p = isA ? pg : pg - 256;
    const float* src = (isA ? a : b) + ((size_t)p * 32 + sub * 16) * 1024;
    int4* out4 = (int4*)(isA ? oa : ob);

    const int r16 = tid >> 4;  // 0..15 row in half-panel
    const int c16 = tid & 15;  // 0..15 chunk
    if (bid == 0 && tid == 0) dout[0] = 0.f;
    if (isA && tid < 16) {
      const int row = p * 32 + sub * 16 + tid;
      pos_acc[row] = 0.f;
      neg_acc[row] = 0.f;
    }

    const float4* inr = (const float4*)(src + (size_t)r16 * 1024);
    float4 v[16];
#pragma unroll
    for (int i = 0; i < 16; i++) v[i] = inr[c16 + 16 * i];
    float ss = 0.f;
#pragma unroll
    for (int i = 0; i < 16; i++)
      ss += v[i].x * v[i].x + v[i].y * v[i].y + v[i].z * v[i].z +
            v[i].w * v[i].w;
#pragma unroll
    for (int m = 8; m >= 1; m >>= 1) ss += __shfl_xor(ss, m, 16);
    const float inv = 32.0f / fmaxf(sqrtf(ss), 1e-12f);

    // pack into LDS: rec i (=k-step), half hi_, row r16, short j_
    unsigned short* pk = (unsigned short*)sA;  // 8 KB used
    const int hi_ = (c16 >> 3) & 1;
    const int j_ = c16 & 7;
#pragma unroll
    for (int i = 0; i < 16; i++) {
      const int n0 = fp4e(v[i].x * inv);
      const int n1 = fp4e(v[i].y * inv);
      const int n2 = fp4e(v[i].z * inv);
      const int n3 = fp4e(v[i].w * inv);
      const unsigned short h =
          (unsigned short)(n0 | (n1 << 4) | (n2 << 8) | (n3 << 12));
      pk[i * 256 + hi_ * 128 + r16 * 8 + j_] = h;
    }
    __syncthreads();
    // copy-out: 32 runs x 256 B; int4 v4: i=v4>>5, hi2=(v4>>4)&1
    const int4* sp4 = (const int4*)pk;
#pragma unroll
    for (int w = 0; w < 2; w++) {
      const int v4 = tid + 256 * w;  // 0..511
      const int i = v4 >> 5;
      const int hi2 = (v4 >> 4) & 1;
      out4[(size_t)(p * 16 + i) * 64 + hi2 * 32 + sub * 16 + (v4 & 15)] =
          sp4[v4];
    }
    __syncthreads();  // LDS reuse safety before phase 2
  }

  cg::this_grid().sync();

  // ---------------- Phase 2: 4 GEMM tiles ----------------
  {
    const int lane = tid & 63;
    const int wave = tid >> 6;
    const int wa = wave >> 1;  // A half (64 rows)
    const int wb = wave & 1;   // B half (64 cols)
    const int xcd = bid & 7;
    const int local = bid >> 3;              // 0..127
    const int by = xcd * 8 + (local & 7);    // 0..63
    const int bxg = local >> 3;              // 0..15
    const int row0 = by * 128;

    const int sr1k = ((tid >> 6) & 3) * 1024 + (tid & 63) * 16;
    const unsigned char* gA = oa + (size_t)by * 65536 + sr1k;

    const int lofs = lane * 16;
    const int aoff0 = (wa * 2 + 0) * 4096 + lofs;
    const int aoff1 = (wa * 2 + 1) * 4096 + lofs;
    const int boff0 = (wb * 2 + 0) * 4096 + lofs;
    const int boff1 = (wb * 2 + 1) * 4096 + lofs;

    const int l31 = lane & 31;
    const int hi = lane >> 5;
    const int rowbase = row0 + wa * 64 + l31;
    const int lav0 = la[rowbase];
    const int lav1 = la[rowbase + 32];

#define STAGE(kt)                                                   \
  do {                                                              \
    _Pragma("unroll") for (int u = 0; u < 4; u++) {                 \
      async16(gA + (size_t)u * 16384 + (size_t)(kt)*4096,           \
              &sA[u * 4096 + tid * 16]);                            \
      async16(gB + (size_t)u * 16384 + (size_t)(kt)*4096,           \
              &sB[u * 4096 + tid * 16]);                            \
    }                                                               \
  } while (0)

#define LD16(dst, base, off)                                        \
  do {                                                              \
    frag32 _f;                                                      \
    _f.s.lo = *(const i32x4*)((base) + (off));                      \
    _f.s.hi = (i32x4){0, 0, 0, 0};                                  \
    dst = _f.v8;                                                    \
  } while (0)

#define MFMA(ci, x_, y_)                                            \
  ci = __builtin_amdgcn_mfma_scale_f32_32x32x64_f8f6f4(             \
      x_, y_, ci, 4, 4, 0, UNIT_SCALE, 0, UNIT_SCALE)

#pragma unroll 1
    for (int t = 0; t < 4; ++t) {
      const int bx = bxg * 4 + t;
      const int col0 = bx * 128;
      const unsigned char* gB = ob + (size_t)bx * 65536 + sr1k;

      f32x16 acc[2][2] = {};  // [bi][aj]

#pragma unroll 1
      for (int kt = 0; kt < 4; ++kt) {
        STAGE(kt);
        __syncthreads();
#pragma unroll
        for (int sp = 0; sp < 4; ++sp) {
          i32x8 fa0, fa1, fb0, fb1;
          LD16(fa0, sA, aoff0 + sp * 1024);
          LD16(fa1, sA, aoff1 + sp * 1024);
          LD16(fb0, sB, boff0 + sp * 1024);
          LD16(fb1, sB, boff1 + sp * 1024);
          // swapped operands: lane&31 <- A-row, regs <- B-col
          MFMA(acc[0][0], fb0, fa0);
          MFMA(acc[0][1], fb0, fa1);
          MFMA(acc[1][0], fb1, fa0);
          MFMA(acc[1][1], fb1, fa1);
        }
        __syncthreads();
      }

      // epilogue (R11 verified): lane-local column sums
      const int colw = col0 + wb * 64 + 4 * hi;
      int lbs[2][16];
#pragma unroll
      for (int bi = 0; bi < 2; bi++)
#pragma unroll
        for (int r = 0; r < 16; r++)
          lbs[bi][r] = lb[colw + bi * 32 + (r & 3) + 8 * (r >> 2)];

#pragma unroll
      for (int aj = 0; aj < 2; aj++) {
        const int lav = aj ? lav1 : lav0;
        float sn = 0.f, sp = 0.f;
#pragma unroll
        for (int bi = 0; bi < 2; bi++)
#pragma unroll
          for (int r = 0; r < 16; r++) {
            const float e = __expf(acc[bi][aj][r] * SCALE_EPI);  // |s|<50
            sn += e;
            sp += (lav == lbs[bi][r]) ? e : 0.f;
          }
        sn += __shfl_xor(sn, 32, 64);
        sp += __shfl_xor(sp, 32, 64);
        if (hi == 0) {
          const int row = rowbase + aj * 32;
          atomicAdd(&neg_acc[row], sn);
          atomicAdd(&pos_acc[row], sp);
        }
      }
    }
  }

  cg::this_grid().sync();

  // ---------------- Phase 3: final reduce (blocks 0..7) ----------------
  if (bid < 8) {
    const int i = bid * 256 + tid;  // 0..2047
    const float4 p4 = ((const float4*)pos_acc)[i];
    const float4 n4 = ((const float4*)neg_acc)[i];
    float local = (logf(n4.x) - logf(fmaxf(p4.x, 1e-8f))) +
                  (logf(n4.y) - logf(fmaxf(p4.y, 1e-8f))) +
                  (logf(n4.z) - logf(fmaxf(p4.z, 1e-8f))) +
                  (logf(n4.w) - logf(fmaxf(p4.w, 1e-8f)));
#pragma unroll
    for (int m = 32; m >= 1; m >>= 1) local += __shfl_xor(local, m, 64);
    __shared__ float ws[4];
    const int wv = tid >> 6, lane = tid & 63;
    if (lane == 0) ws[wv] = local;
    __syncthreads();
    if (tid == 0)
      atomicAdd(dout, (ws[0] + ws[1] + ws[2] + ws[3]) * (1.0f / 8192.0f));
  }
}

// ============================================================
// Fallback path (R11 verbatim): used only if cooperative launch
// is rejected by the runtime.
// ============================================================
__global__ __launch_bounds__(1024) void normalize_rows(
    const float* __restrict__ a, const float* __restrict__ b,
    int* __restrict__ oa, int* __restrict__ ob,
    float* __restrict__ pos_acc, float* __restrict__ neg_acc,
    float* __restrict__ dout, int N, int D) {
  __shared__ __align__(16) unsigned short sPk[8192];
  const int blk = blockIdx.x;
  const bool isA = blk < 256;
  const int p = isA ? blk : blk - 256;
  const float* src = (isA ? a : b) + (size_t)p * 32 * D;
  int* out = isA ? oa : ob;
  const int tid = threadIdx.x;
  const int r = tid >> 5, c = tid & 31;
  if (blk == 0 && tid == 0) dout[0] = 0.f;
  if (isA && c == 0) {
    pos_acc[p * 32 + r] = 0.f;
    neg_acc[p * 32 + r] = 0.f;
  }
  const float4* inr = (const float4*)(src + (size_t)r * D);
  float4 v[8];
#pragma unroll
  for (int i = 0; i < 8; i++) v[i] = inr[c + 32 * i];
  float ss = 0.f;
#pragma unroll
  for (int i = 0; i < 8; i++)
    ss += v[i].x * v[i].x + v[i].y * v[i].y + v[i].z * v[i].z + v[i].w * v[i].w;
#pragma unroll
  for (int m = 16; m >= 1; m >>= 1) ss += __shfl_xor(ss, m, 32);
  const float inv = 32.0f / fmaxf(sqrtf(ss), 1e-12f);
#pragma unroll
  for (int i = 0; i < 8; i++) {
    const int n0 = fp4e(v[i].x * inv);
    const int n1 = fp4e(v[i].y * inv);
    const int n2 = fp4e(v[i].z * inv);
    const int n3 = fp4e(v[i].w * inv);
    const unsigned short h =
        (unsigned short)(n0 | (n1 << 4) | (n2 << 8) | (n3 << 12));
    const int f = c + 32 * i;
    sPk[(f >> 4) * 512 + (((f >> 3) & 1) * 32 + r) * 8 + (f & 7)] = h;
  }
  __syncthreads();
  const int4* sp4 = (const int4*)sPk;
  int4* op4 = (int4*)(out + (size_t)p * 2048);
#pragma unroll
  for (int j = 0; j < 1; j++) op4[tid] = sp4[tid];
}

__global__ __launch_bounds__(256, 4) void infonce_gemm(
    const unsigned char* __restrict__ A, const unsigned char* __restrict__ B,
    const int* __restrict__ la, const int* __restrict__ lb,
    float* __restrict__ pos_acc, float* __restrict__ neg_acc) {
  __shared__ __align__(16) unsigned char sA[16384];
  __shared__ __align__(16) unsigned char sB[16384];
  const int tid = threadIdx.x;
  const int lane = tid & 63;
  const int wave = tid >> 6;
  const int wa = wave >> 1, wb = wave & 1;
  const int bid = blockIdx.x;
  const int xcd = bid & 7, local = bid >> 3;
  const int by = xcd * 8 + (local & 7);
  const int bx = local >> 3;
  const int row0 = by * 128, col0 = bx * 128;
  const int sr1k = ((tid >> 6) & 3) * 1024 + (tid & 63) * 16;
  const unsigned char* gA = A + (size_t)by * 65536 + sr1k;
  const unsigned char* gB = B + (size_t)bx * 65536 + sr1k;
  f32x16 acc[2][2] = {};
  const int lofs = lane * 16;
  const int aoff0 = (wa * 2 + 0) * 4096 + lofs;
  const int aoff1 = (wa * 2 + 1) * 4096 + lofs;
  const int boff0 = (wb * 2 + 0) * 4096 + lofs;
  const int boff1 = (wb * 2 + 1) * 4096 + lofs;
#pragma unroll 1
  for (int kt = 0; kt < 4; ++kt) {
    STAGE(kt);
    __syncthreads();
#pragma unroll
    for (int sp = 0; sp < 4; ++sp) {
      i32x8 fa0, fa1, fb0, fb1;
      LD16(fa0, sA, aoff0 + sp * 1024);
      LD16(fa1, sA, aoff1 + sp * 1024);
      LD16(fb0, sB, boff0 + sp * 1024);
      LD16(fb1, sB, boff1 + sp * 1024);
      MFMA(acc[0][0], fb0, fa0);
      MFMA(acc[0][1], fb0, fa1);
      MFMA(acc[1][0], fb1, fa0);
      MFMA(acc[1][1], fb1, fa1);
    }
    __syncthreads();
  }
  const int l31 = lane & 31;
  const int hi = lane >> 5;
  const int colw = col0 + wb * 64 + 4 * hi;
  const int rowbase = row0 + wa * 64 + l31;
  const int lav0 = la[rowbase];
  const int lav1 = la[rowbase + 32];
  int lbs[2][16];
#pragma unroll
  for (int bi = 0; bi < 2; bi++)
#pragma unroll
    for (int r = 0; r < 16; r++)
      lbs[bi][r] = lb[colw + bi * 32 + (r & 3) + 8 * (r >> 2)];
#pragma unroll
  for (int aj = 0; aj < 2; aj++) {
    const int lav = aj ? lav1 : lav0;
    float sn = 0.f, sp = 0.f;
#pragma unroll
    for (int bi = 0; bi < 2; bi++)
#pragma unroll
      for (int r = 0; r < 16; r++) {
        const float e = __expf(acc[bi][aj][r] * SCALE_EPI);
        sn += e;
        sp += (lav == lbs[bi][r]) ? e : 0.f;
      }
    sn += __shfl_xor(sn, 32, 64);
    sp += __shfl_xor(sp, 32, 64);
    if (hi == 0) {
      const int row = rowbase + aj * 32;
      atomicAdd(&neg_acc[row], sn);
      atomicAdd(&pos_acc[row], sp);
    }
  }
}

__global__ __launch_bounds__(256) void final_reduce(
    const float* __restrict__ pos, const float* __restrict__ neg,
    float* __restrict__ out, int N) {
  const int i = blockIdx.x * 256 + threadIdx.x;
  const float4 p4 = ((const float4*)pos)[i];
  const float4 n4 = ((const float4*)neg)[i];
  float local = (logf(n4.x) - logf(fmaxf(p4.x, 1e-8f))) +
                (logf(n4.y) - logf(fmaxf(p4.y, 1e-8f))) +
                (logf(n4.z) - logf(fmaxf(p4.z, 1e-8f))) +
                (logf(n4.w) - logf(fmaxf(p4.w, 1e-8f)));
#pragma unroll
  for (int m = 32; m >= 1; m >>= 1) local += __shfl_xor(local, m, 64);
  __shared__ float ws[4];
  const int wv = threadIdx.x >> 6, lane = threadIdx.x & 63;
  if (lane == 0) ws[wv] = local;
  __syncthreads();
  if (threadIdx.x == 0)
    atomicAdd(out, (ws[0] + ws[1] + ws[2] + ws[3]) * (1.0f / (float)N));
}

extern "C" void kernel_launch(void* const* d_in, const int* in_sizes, int n_in,
                              void* d_out, int out_size, void* d_ws, size_t ws_size,
                              hipStream_t stream) {
  const float* fa = (const float*)d_in[0];
  const float* fb = (const float*)d_in[1];
  const int* la = (const int*)d_in[2];
  const int* lb = (const int*)d_in[3];

  const int D = 1024;
  const int N = in_sizes[0] / D;  // 8192
  const int M = in_sizes[1] / D;  // 8192

  unsigned char* nA = (unsigned char*)d_ws;            // 4 MB fp4
  unsigned char* nB = nA + (size_t)N * D / 2;          // 4 MB fp4
  float* pos = (float*)(nB + (size_t)M * D / 2);
  float* neg = pos + N;
  float* outp = (float*)d_out;

  void* args[] = {(void*)&fa, (void*)&fb, (void*)&nA, (void*)&nB,
                  (void*)&la, (void*)&lb, (void*)&pos, (void*)&neg,
                  (void*)&outp};
  hipError_t err = hipLaunchCooperativeKernel(
      (const void*)fused_all, dim3(1024), dim3(256), args, 0, stream);
  if (err != hipSuccess) {
    (void)hipGetLastError();  // clear
    normalize_rows<<<512, 1024, 0, stream>>>(fa, fb, (int*)nA, (int*)nB, pos,
                                             neg, outp, N, D);
    infonce_gemm<<<4096, 256, 0, stream>>>(nA, nB, la, lb, pos, neg);
    final_reduce<<<8, 256, 0, stream>>>(pos, neg, outp, N);
  }
}

// Round 13
// 149.304 us; speedup vs baseline: 2.4924x; 2.4924x over previous
//
#include <hip/hip_runtime.h>
#include <hip/hip_bf16.h>
#include <math.h>

typedef __attribute__((ext_vector_type(4))) float f32x4;
typedef __attribute__((ext_vector_type(16))) float f32x16;
typedef __attribute__((ext_vector_type(8))) int i32x8;
typedef __attribute__((ext_vector_type(4))) int i32x4;

#define TEMP_INV 14.2857142857142857f     // 1/0.07
#define SCALE_EPI 0.013950892857142857f   // TEMP_INV / 1024 (32*32 prescale)
#define K2EPI 0.020126883973f             // SCALE_EPI * log2(e): e^sx = 2^(x*K2)
#define UNIT_SCALE 0x7f7f7f7f             // E8M0 127 -> x1.0 exact (verified)

union frag32 {
  i32x8 v8;
  struct { i32x4 lo; i32x4 hi; } s;
};

// ---- async global->LDS, 16B per lane
static __device__ inline void async16(const void* g, void* l) {
  __builtin_amdgcn_global_load_lds(
      (const __attribute__((address_space(1))) unsigned int*)g,
      (__attribute__((address_space(3))) unsigned int*)l,
      16, 0, 0);
}

// ---- OCP fp4 e2m1 encode, branchless (R13):
// code = min(floor(af*2+0.5),4) + (af>2.5)+(af>3.5)+(af>5); sign bit3.
// Equal to the R8-verified threshold chain on all codes (round-half-up
// below 2.0, caps at 4, upper thresholds identical); ties at exact
// boundaries are measure-zero.
static __device__ inline int fp4e(float y) {
  const float af = fabsf(y);
  int code = (int)fminf(fmaf(af, 2.0f, 0.5f), 4.9f);
  code += (af > 2.5f) + (af > 3.5f) + (af > 5.0f);
  return code | ((int)(__float_as_uint(y) >> 28) & 8);
}

// ============================================================
// Fragment-major MX-fp4 format (verified R8-R11: absmax 0.031):
//   panel p = 32 rows, k-step s = 64 K-elems. record(p,s) = 1 KB at
//   (p*16+s)*1024. Lane l: row p*32+(l&31), k-elems s*64+(l>>5)*32..
//   16 B at rec + l*16. Values are 32*x (exact pow-2 prescale).
// ============================================================

// ============================================================
// Kernel 1: L2-normalize rows (D=1024) -> fp4 fragment-major.
// (R11 structure; fp4e swapped for the branchless encoder)
// ============================================================
__global__ __launch_bounds__(1024) void normalize_rows(
    const float* __restrict__ a, const float* __restrict__ b,
    int* __restrict__ oa, int* __restrict__ ob,
    float* __restrict__ pos_acc, float* __restrict__ neg_acc,
    float* __restrict__ dout, int N, int D) {
  __shared__ __align__(16) unsigned short sPk[8192];  // 16 KB

  const int blk = blockIdx.x;          // 0..511
  const bool isA = blk < 256;
  const int p = isA ? blk : blk - 256;
  const float* src = (isA ? a : b) + (size_t)p * 32 * D;
  int* out = isA ? oa : ob;

  const int tid = threadIdx.x;
  const int r = tid >> 5;   // row within panel
  const int c = tid & 31;   // chunk within row

  if (blk == 0 && tid == 0) dout[0] = 0.f;
  if (isA && c == 0) {
    pos_acc[p * 32 + r] = 0.f;
    neg_acc[p * 32 + r] = 0.f;
  }

  const float4* inr = (const float4*)(src + (size_t)r * D);
  float4 v[8];
#pragma unroll
  for (int i = 0; i < 8; i++) v[i] = inr[c + 32 * i];

  float ss = 0.f;
#pragma unroll
  for (int i = 0; i < 8; i++)
    ss += v[i].x * v[i].x + v[i].y * v[i].y + v[i].z * v[i].z + v[i].w * v[i].w;
#pragma unroll
  for (int m = 16; m >= 1; m >>= 1) ss += __shfl_xor(ss, m, 32);
  const float inv = 32.0f / fmaxf(sqrtf(ss), 1e-12f);  // pre-scale by 32

#pragma unroll
  for (int i = 0; i < 8; i++) {
    const int n0 = fp4e(v[i].x * inv);
    const int n1 = fp4e(v[i].y * inv);
    const int n2 = fp4e(v[i].z * inv);
    const int n3 = fp4e(v[i].w * inv);
    const unsigned short h =
        (unsigned short)(n0 | (n1 << 4) | (n2 << 8) | (n3 << 12));
    const int f = c + 32 * i;  // 2B-group index
    sPk[(f >> 4) * 512 + (((f >> 3) & 1) * 32 + r) * 8 + (f & 7)] = h;
  }
  __syncthreads();

  // linear copy-out: 16 KB = 1024 int4, one per thread
  const int4* sp4 = (const int4*)sPk;
  ((int4*)out)[(size_t)p * 1024 + tid] = sp4[tid];
}

// ============================================================
// Kernel 2: fused MX-fp4 MFMA GEMM + exp epilogue.
// R13 = R11 (best GEMM: 50.0 us) + setprio around the MFMA quartet
// (builtin only; R5 precedent at VGPR 52-56, no spill) + exp2f with
// prefolded log2e constant in the epilogue. Everything else identical:
// (256,4) envelope, BK=256, 4 blocks/CU, swapped-operand epilogue
// (lane-local column sums), bijective XCD rectangle swizzle.
// ============================================================
__global__ __launch_bounds__(256, 4) void infonce_gemm(
    const unsigned char* __restrict__ A, const unsigned char* __restrict__ B,
    const int* __restrict__ la, const int* __restrict__ lb,
    float* __restrict__ pos_acc, float* __restrict__ neg_acc) {
  __shared__ __align__(16) unsigned char sA[16384];
  __shared__ __align__(16) unsigned char sB[16384];

  const int tid = threadIdx.x;
  const int lane = tid & 63;
  const int wave = tid >> 6;  // 0..3
  const int wa = wave >> 1;   // 0..1 (A half: 64 rows)
  const int wb = wave & 1;    // 0..1 (B half: 64 cols)

  // grid 4096 = 64 by x 64 bx; bijective XCD rectangle swizzle
  const int bid = blockIdx.x;
  const int xcd = bid & 7;
  const int local = bid >> 3;              // 0..511
  const int by = xcd * 8 + (local & 7);    // 0..63
  const int bx = local >> 3;               // 0..63
  const int row0 = by * 128;
  const int col0 = bx * 128;

  // staging: 4 panels x 4 records per iter; tid covers record
  // sr=(tid>>6)&3, inner (tid&63)*16; panel u unrolled.
  const int sr1k = ((tid >> 6) & 3) * 1024 + (tid & 63) * 16;
  const unsigned char* gA = A + (size_t)by * 65536 + sr1k;
  const unsigned char* gB = B + (size_t)bx * 65536 + sr1k;

  f32x16 acc[2][2] = {};  // [bi][aj]

#define STAGE(kt)                                                   \
  do {                                                              \
    _Pragma("unroll") for (int u = 0; u < 4; u++) {                 \
      async16(gA + (size_t)u * 16384 + (size_t)(kt)*4096,           \
              &sA[u * 4096 + tid * 16]);                            \
      async16(gB + (size_t)u * 16384 + (size_t)(kt)*4096,           \
              &sB[u * 4096 + tid * 16]);                            \
    }                                                               \
  } while (0)

// fp4 fragment: ONE b128 (16 B = 32 fp4), upper operand regs zero
#define LD16(dst, base, off)                                        \
  do {                                                              \
    frag32 _f;                                                      \
    _f.s.lo = *(const i32x4*)((base) + (off));                      \
    _f.s.hi = (i32x4){0, 0, 0, 0};                                  \
    dst = _f.v8;                                                    \
  } while (0)

#define MFMA(ci, x_, y_)                                            \
  ci = __builtin_amdgcn_mfma_scale_f32_32x32x64_f8f6f4(             \
      x_, y_, ci, 4, 4, 0, UNIT_SCALE, 0, UNIT_SCALE)

  const int lofs = lane * 16;
  const int aoff0 = (wa * 2 + 0) * 4096 + lofs;  // + sp*1024
  const int aoff1 = (wa * 2 + 1) * 4096 + lofs;
  const int boff0 = (wb * 2 + 0) * 4096 + lofs;
  const int boff1 = (wb * 2 + 1) * 4096 + lofs;

#pragma unroll 1
  for (int kt = 0; kt < 4; ++kt) {
    STAGE(kt);
    __syncthreads();  // tile resident
#pragma unroll
    for (int sp = 0; sp < 4; ++sp) {
      i32x8 fa0, fa1, fb0, fb1;
      LD16(fa0, sA, aoff0 + sp * 1024);
      LD16(fa1, sA, aoff1 + sp * 1024);
      LD16(fb0, sB, boff0 + sp * 1024);
      LD16(fb1, sB, boff1 + sp * 1024);
      // swapped operands: lane&31 <- A-row, regs <- B-col
      __builtin_amdgcn_s_setprio(1);
      MFMA(acc[0][0], fb0, fa0);
      MFMA(acc[0][1], fb0, fa1);
      MFMA(acc[1][0], fb1, fa0);
      MFMA(acc[1][1], fb1, fa1);
      __builtin_amdgcn_s_setprio(0);
    }
    __syncthreads();  // reads done before next STAGE overwrites
  }

  // ---- epilogue (R11 verified): lane l31 = A-row, lane-local col sums
  const int l31 = lane & 31;
  const int hi = lane >> 5;
  const int colw = col0 + wb * 64 + 4 * hi;
  const int rowbase = row0 + wa * 64 + l31;

  const int lav0 = la[rowbase];
  const int lav1 = la[rowbase + 32];

  int lbs[2][16];
#pragma unroll
  for (int bi = 0; bi < 2; bi++)
#pragma unroll
    for (int r = 0; r < 16; r++)
      lbs[bi][r] = lb[colw + bi * 32 + (r & 3) + 8 * (r >> 2)];

#pragma unroll
  for (int aj = 0; aj < 2; aj++) {
    const int lav = aj ? lav1 : lav0;
    float sn = 0.f, sp = 0.f;
#pragma unroll
    for (int bi = 0; bi < 2; bi++)
#pragma unroll
      for (int r = 0; r < 16; r++) {
        const float e = exp2f(acc[bi][aj][r] * K2EPI);  // e^(s/T), |s/T|<50
        sn += e;
        sp += (lav == lbs[bi][r]) ? e : 0.f;
      }
    sn += __shfl_xor(sn, 32, 64);
    sp += __shfl_xor(sp, 32, 64);
    if (hi == 0) {
      const int row = rowbase + aj * 32;
      atomicAdd(&neg_acc[row], sn);
      atomicAdd(&pos_acc[row], sp);
    }
  }
}

// ============================================================
// Kernel 3: loss partials -> atomic mean. 8 blocks x 256 thr.
// out[0] zeroed by normalize (stream-ordered).
// ============================================================
__global__ __launch_bounds__(256) void final_reduce(
    const float* __restrict__ pos, const float* __restrict__ neg,
    float* __restrict__ out, int N) {
  const int i = blockIdx.x * 256 + threadIdx.x;  // 0..2047
  const float4 p4 = ((const float4*)pos)[i];
  const float4 n4 = ((const float4*)neg)[i];
  float local = (logf(n4.x) - logf(fmaxf(p4.x, 1e-8f))) +
                (logf(n4.y) - logf(fmaxf(p4.y, 1e-8f))) +
                (logf(n4.z) - logf(fmaxf(p4.z, 1e-8f))) +
                (logf(n4.w) - logf(fmaxf(p4.w, 1e-8f)));
#pragma unroll
  for (int m = 32; m >= 1; m >>= 1) local += __shfl_xor(local, m, 64);
  __shared__ float ws[4];
  const int wv = threadIdx.x >> 6, lane = threadIdx.x & 63;
  if (lane == 0) ws[wv] = local;
  __syncthreads();
  if (threadIdx.x == 0)
    atomicAdd(out, (ws[0] + ws[1] + ws[2] + ws[3]) * (1.0f / (float)N));
}

extern "C" void kernel_launch(void* const* d_in, const int* in_sizes, int n_in,
                              void* d_out, int out_size, void* d_ws, size_t ws_size,
                              hipStream_t stream) {
  const float* fa = (const float*)d_in[0];
  const float* fb = (const float*)d_in[1];
  const int* la = (const int*)d_in[2];
  const int* lb = (const int*)d_in[3];

  const int D = 1024;
  const int N = in_sizes[0] / D;  // 8192
  const int M = in_sizes[1] / D;  // 8192

  unsigned char* nA = (unsigned char*)d_ws;            // 4 MB fp4
  unsigned char* nB = nA + (size_t)N * D / 2;          // 4 MB fp4
  float* pos = (float*)(nB + (size_t)M * D / 2);
  float* neg = pos + N;

  normalize_rows<<<512, 1024, 0, stream>>>(fa, fb, (int*)nA, (int*)nB, pos,
                                           neg, (float*)d_out, N, D);

  infonce_gemm<<<4096, 256, 0, stream>>>(nA, nB, la, lb, pos, neg);

  final_reduce<<<8, 256, 0, stream>>>(pos, neg, (float*)d_out, N);
}

// Round 14
// 145.042 us; speedup vs baseline: 2.5656x; 1.0294x over previous
//
#include <hip/hip_runtime.h>
#include <hip/hip_bf16.h>
#include <math.h>

typedef __attribute__((ext_vector_type(4))) float f32x4;
typedef __attribute__((ext_vector_type(16))) float f32x16;
typedef __attribute__((ext_vector_type(8))) int i32x8;
typedef __attribute__((ext_vector_type(4))) int i32x4;

#define TEMP_INV 14.2857142857142857f     // 1/0.07
#define SCALE_EPI 0.013950892857142857f   // TEMP_INV / 1024 (32*32 prescale)
#define K2EPI 0.020126883973f             // SCALE_EPI * log2(e)
#define UNIT_SCALE 0x7f7f7f7f             // E8M0 127 -> x1.0 exact (verified)

union frag32 {
  i32x8 v8;
  struct { i32x4 lo; i32x4 hi; } s;
};

// ---- async global->LDS, 16B per lane
static __device__ inline void async16(const void* g, void* l) {
  __builtin_amdgcn_global_load_lds(
      (const __attribute__((address_space(1))) unsigned int*)g,
      (__attribute__((address_space(3))) unsigned int*)l,
      16, 0, 0);
}

// ---- OCP fp4 e2m1 encode, branchless (R13-verified: absmax 0.031)
static __device__ inline int fp4e(float y) {
  const float af = fabsf(y);
  int code = (int)fminf(fmaf(af, 2.0f, 0.5f), 4.9f);
  code += (af > 2.5f) + (af > 3.5f) + (af > 5.0f);
  return code | ((int)(__float_as_uint(y) >> 28) & 8);
}

// ============================================================
// Fragment-major MX-fp4 format (verified R8-R13):
//   panel p = 32 rows, k-step s = 64 K-elems. record(p,s) = 1 KB at
//   (p*16+s)*1024. Lane l: row p*32+(l&31), k-elems s*64+(l>>5)*32..
//   16 B at rec + l*16. Values are 32*x (exact pow-2 prescale).
// ============================================================

// ============================================================
// Kernel 1: L2-normalize rows (D=1024) -> fp4 fragment-major.
// (R13 version: branchless encoder; verified absmax 0.031)
// ============================================================
__global__ __launch_bounds__(1024) void normalize_rows(
    const float* __restrict__ a, const float* __restrict__ b,
    int* __restrict__ oa, int* __restrict__ ob,
    float* __restrict__ pos_acc, float* __restrict__ neg_acc,
    float* __restrict__ dout, int N, int D) {
  __shared__ __align__(16) unsigned short sPk[8192];  // 16 KB

  const int blk = blockIdx.x;          // 0..511
  const bool isA = blk < 256;
  const int p = isA ? blk : blk - 256;
  const float* src = (isA ? a : b) + (size_t)p * 32 * D;
  int* out = isA ? oa : ob;

  const int tid = threadIdx.x;
  const int r = tid >> 5;   // row within panel
  const int c = tid & 31;   // chunk within row

  if (blk == 0 && tid == 0) dout[0] = 0.f;
  if (isA && c == 0) {
    pos_acc[p * 32 + r] = 0.f;
    neg_acc[p * 32 + r] = 0.f;
  }

  const float4* inr = (const float4*)(src + (size_t)r * D);
  float4 v[8];
#pragma unroll
  for (int i = 0; i < 8; i++) v[i] = inr[c + 32 * i];

  float ss = 0.f;
#pragma unroll
  for (int i = 0; i < 8; i++)
    ss += v[i].x * v[i].x + v[i].y * v[i].y + v[i].z * v[i].z + v[i].w * v[i].w;
#pragma unroll
  for (int m = 16; m >= 1; m >>= 1) ss += __shfl_xor(ss, m, 32);
  const float inv = 32.0f / fmaxf(sqrtf(ss), 1e-12f);  // pre-scale by 32

#pragma unroll
  for (int i = 0; i < 8; i++) {
    const int n0 = fp4e(v[i].x * inv);
    const int n1 = fp4e(v[i].y * inv);
    const int n2 = fp4e(v[i].z * inv);
    const int n3 = fp4e(v[i].w * inv);
    const unsigned short h =
        (unsigned short)(n0 | (n1 << 4) | (n2 << 8) | (n3 << 12));
    const int f = c + 32 * i;  // 2B-group index
    sPk[(f >> 4) * 512 + (((f >> 3) & 1) * 32 + r) * 8 + (f & 7)] = h;
  }
  __syncthreads();

  const int4* sp4 = (const int4*)sPk;
  ((int4*)out)[(size_t)p * 1024 + tid] = sp4[tid];
}

// ============================================================
// Kernel 2: fused MX-fp4 MFMA GEMM + exp epilogue.
// R14: B OUT OF LDS. A stays global_load_lds-staged (16 KB LDS);
// B fragments load global->register (8 x dwordx4 per K-tile, issued
// BEFORE __syncthreads so the barrier's vmcnt drain makes them
// resident exactly when compute starts — L2 latency overlaps the
// A-staging drain; compiler-managed waits only, no inline asm).
//  * barrier-coupled LDS traffic per block-iter: 96 -> 48 KB
//  * L2 B-reads 2x-redundant: ~512 MB total ~= 55% per-CU L2 share
//  * regs: acc 64 + B-frags 32 + A-frags ~12 + addr ~16 <= 128 @(256,4)
// Envelope unchanged: 128x128 tile, 4 waves 2x2, BK=256, 4 blocks/CU,
// bijective XCD rectangle swizzle, R11 swapped-operand epilogue.
// No setprio (R13: null/negative).
// ============================================================
__global__ __launch_bounds__(256, 4) void infonce_gemm(
    const unsigned char* __restrict__ A, const unsigned char* __restrict__ B,
    const int* __restrict__ la, const int* __restrict__ lb,
    float* __restrict__ pos_acc, float* __restrict__ neg_acc) {
  __shared__ __align__(16) unsigned char sA[16384];

  const int tid = threadIdx.x;
  const int lane = tid & 63;
  const int wave = tid >> 6;  // 0..3
  const int wa = wave >> 1;   // 0..1 (A half: 64 rows)
  const int wb = wave & 1;    // 0..1 (B half: 64 cols)

  // grid 4096 = 64 by x 64 bx; bijective XCD rectangle swizzle
  const int bid = blockIdx.x;
  const int xcd = bid & 7;
  const int local = bid >> 3;              // 0..511
  const int by = xcd * 8 + (local & 7);    // 0..63
  const int bx = local >> 3;               // 0..63
  const int row0 = by * 128;
  const int col0 = bx * 128;

  // A staging: 4 panels x 4 records per K-tile; tid covers record
  // sr=(tid>>6)&3, inner (tid&63)*16; panel u unrolled.
  const int sr1k = ((tid >> 6) & 3) * 1024 + (tid & 63) * 16;
  const unsigned char* gA = A + (size_t)by * 65536 + sr1k;

  // B per-lane fragment base: record(pb=wb*2+bi, s=kt*4+sp) at
  // B + bx*65536 + pb*16384 + s*1024 + lane*16
  const unsigned char* gB0 = B + (size_t)bx * 65536 + wb * 32768 + lane * 16;

  f32x16 acc[2][2] = {};  // [bi][aj]

#define STAGEA(kt)                                                  \
  do {                                                              \
    _Pragma("unroll") for (int u = 0; u < 4; u++) {                 \
      async16(gA + (size_t)u * 16384 + (size_t)(kt)*4096,           \
              &sA[u * 4096 + tid * 16]);                            \
    }                                                               \
  } while (0)

// fp4 A fragment from LDS: ONE b128, upper operand regs zero
#define LD16(dst, base, off)                                        \
  do {                                                              \
    frag32 _f;                                                      \
    _f.s.lo = *(const i32x4*)((base) + (off));                      \
    _f.s.hi = (i32x4){0, 0, 0, 0};                                  \
    dst = _f.v8;                                                    \
  } while (0)

// widen a register-held B i32x4 to the 8-reg operand (hi zero)
#define W8(dst, q)                                                  \
  do {                                                              \
    frag32 _f;                                                      \
    _f.s.lo = (q);                                                  \
    _f.s.hi = (i32x4){0, 0, 0, 0};                                  \
    dst = _f.v8;                                                    \
  } while (0)

#define MFMA(ci, x_, y_)                                            \
  ci = __builtin_amdgcn_mfma_scale_f32_32x32x64_f8f6f4(             \
      x_, y_, ci, 4, 4, 0, UNIT_SCALE, 0, UNIT_SCALE)

  const int lofs = lane * 16;
  const int aoff0 = (wa * 2 + 0) * 4096 + lofs;  // + sp*1024
  const int aoff1 = (wa * 2 + 1) * 4096 + lofs;

#pragma unroll 1
  for (int kt = 0; kt < 4; ++kt) {
    STAGEA(kt);
    // issue all 8 B-fragment loads for this K-tile (global->reg);
    // the barrier's vmcnt drain below makes them resident for compute.
    const unsigned char* gBF = gB0 + (size_t)kt * 4096;
    const i32x4 b00 = *(const i32x4*)(gBF);
    const i32x4 b01 = *(const i32x4*)(gBF + 16384);
    const i32x4 b10 = *(const i32x4*)(gBF + 1024);
    const i32x4 b11 = *(const i32x4*)(gBF + 16384 + 1024);
    const i32x4 b20 = *(const i32x4*)(gBF + 2048);
    const i32x4 b21 = *(const i32x4*)(gBF + 16384 + 2048);
    const i32x4 b30 = *(const i32x4*)(gBF + 3072);
    const i32x4 b31 = *(const i32x4*)(gBF + 16384 + 3072);
    __syncthreads();  // A tile resident; B regs resident

#define SPSTEP(sp_, q0, q1)                                         \
    do {                                                            \
      i32x8 fa0, fa1, fb0, fb1;                                     \
      LD16(fa0, sA, aoff0 + (sp_)*1024);                            \
      LD16(fa1, sA, aoff1 + (sp_)*1024);                            \
      W8(fb0, q0);                                                  \
      W8(fb1, q1);                                                  \
      MFMA(acc[0][0], fb0, fa0);                                    \
      MFMA(acc[0][1], fb0, fa1);                                    \
      MFMA(acc[1][0], fb1, fa0);                                    \
      MFMA(acc[1][1], fb1, fa1);                                    \
    } while (0)

    SPSTEP(0, b00, b01);
    SPSTEP(1, b10, b11);
    SPSTEP(2, b20, b21);
    SPSTEP(3, b30, b31);
#undef SPSTEP

    __syncthreads();  // A reads done before next STAGEA overwrites
  }

  // ---- epilogue (R11 verified): lane l31 = A-row, lane-local col sums
  const int l31 = lane & 31;
  const int hi = lane >> 5;
  const int colw = col0 + wb * 64 + 4 * hi;
  const int rowbase = row0 + wa * 64 + l31;

  const int lav0 = la[rowbase];
  const int lav1 = la[rowbase + 32];

  int lbs[2][16];
#pragma unroll
  for (int bi = 0; bi < 2; bi++)
#pragma unroll
    for (int r = 0; r < 16; r++)
      lbs[bi][r] = lb[colw + bi * 32 + (r & 3) + 8 * (r >> 2)];

#pragma unroll
  for (int aj = 0; aj < 2; aj++) {
    const int lav = aj ? lav1 : lav0;
    float sn = 0.f, sp = 0.f;
#pragma unroll
    for (int bi = 0; bi < 2; bi++)
#pragma unroll
      for (int r = 0; r < 16; r++) {
        const float e = exp2f(acc[bi][aj][r] * K2EPI);  // e^(s/T), |s/T|<50
        sn += e;
        sp += (lav == lbs[bi][r]) ? e : 0.f;
      }
    sn += __shfl_xor(sn, 32, 64);
    sp += __shfl_xor(sp, 32, 64);
    if (hi == 0) {
      const int row = rowbase + aj * 32;
      atomicAdd(&neg_acc[row], sn);
      atomicAdd(&pos_acc[row], sp);
    }
  }
}

// ============================================================
// Kernel 3: loss partials -> atomic mean. 8 blocks x 256 thr.
// out[0] zeroed by normalize (stream-ordered).
// ============================================================
__global__ __launch_bounds__(256) void final_reduce(
    const float* __restrict__ pos, const float* __restrict__ neg,
    float* __restrict__ out, int N) {
  const int i = blockIdx.x * 256 + threadIdx.x;  // 0..2047
  const float4 p4 = ((const float4*)pos)[i];
  const float4 n4 = ((const float4*)neg)[i];
  float local = (logf(n4.x) - logf(fmaxf(p4.x, 1e-8f))) +
                (logf(n4.y) - logf(fmaxf(p4.y, 1e-8f))) +
                (logf(n4.z) - logf(fmaxf(p4.z, 1e-8f))) +
                (logf(n4.w) - logf(fmaxf(p4.w, 1e-8f)));
#pragma unroll
  for (int m = 32; m >= 1; m >>= 1) local += __shfl_xor(local, m, 64);
  __shared__ float ws[4];
  const int wv = threadIdx.x >> 6, lane = threadIdx.x & 63;
  if (lane == 0) ws[wv] = local;
  __syncthreads();
  if (threadIdx.x == 0)
    atomicAdd(out, (ws[0] + ws[1] + ws[2] + ws[3]) * (1.0f / (float)N));
}

extern "C" void kernel_launch(void* const* d_in, const int* in_sizes, int n_in,
                              void* d_out, int out_size, void* d_ws, size_t ws_size,
                              hipStream_t stream) {
  const float* fa = (const float*)d_in[0];
  const float* fb = (const float*)d_in[1];
  const int* la = (const int*)d_in[2];
  const int* lb = (const int*)d_in[3];

  const int D = 1024;
  const int N = in_sizes[0] / D;  // 8192
  const int M = in_sizes[1] / D;  // 8192

  unsigned char* nA = (unsigned char*)d_ws;            // 4 MB fp4
  unsigned char* nB = nA + (size_t)N * D / 2;          // 4 MB fp4
  float* pos = (float*)(nB + (size_t)M * D / 2);
  float* neg = pos + N;

  normalize_rows<<<512, 1024, 0, stream>>>(fa, fb, (int*)nA, (int*)nB, pos,
                                           neg, (float*)d_out, N, D);

  infonce_gemm<<<4096, 256, 0, stream>>>(nA, nB, la, lb, pos, neg);

  final_reduce<<<8, 256, 0, stream>>>(pos, neg, (float*)d_out, N);
}